// Round 1
// baseline (148.539 us; speedup 1.0000x reference)
//
#include <hip/hip_runtime.h>

#define B 16
#define S 4096
#define V 128
#define TRUNC 11
#define T_LIM (S - TRUNC)   // 4085

// log2(0.99)
#define LOG2_GAMMA (-0.014499569695115089f)
// 1/0.99
#define INV_GAMMA 1.0101010101010102f

__device__ __forceinline__ float log_sigmoid(float x) {
    // min(x,0) - log1p(exp(-|x|)); fast-math variants are fine at 2% tolerance
    float e = __expf(-fabsf(x));
    return fminf(x, 0.0f) - __logf(1.0f + e);
}

// One thread per (chunk c, batch b, group of 4 v).
// Computes, per v: A = sum_{t in chunk} w[t]*ls[t]*local_acc[t]
//                  W = sum_{t in chunk} w[t]*ls[t]
//                  L = sum_{t in chunk, t<T} lp[t]   (== final local_acc)
// where local_acc[t] = sum_{t' in chunk, t'<=t, t'<T} lp[t'].
__global__ __launch_bounds__(256) void partials_kernel(
    const float4* __restrict__ lp,   // [S][B][V/4]
    const float4* __restrict__ lg,   // [B][S][V/4]
    float4* __restrict__ pA,         // [NC][B][V/4]
    float4* __restrict__ pW,         // may be null (single-chunk direct-out mode)
    float4* __restrict__ pL,
    int NC, int CT)
{
    int tid = blockIdx.x * blockDim.x + threadIdx.x;
    if (tid >= NC * (B * V / 4)) return;
    int v4 = tid & (V / 4 - 1);          // 0..31
    int b  = (tid >> 5) & (B - 1);       // 0..15
    int c  = tid >> 9;                   // chunk
    int t0 = c * CT;

    const float4* lp_p = lp + (size_t)t0 * (B * V / 4) + b * (V / 4) + v4;
    const float4* lg_p = lg + (size_t)b * (S * V / 4) + (size_t)t0 * (V / 4) + v4;

    // w[t] = gamma^(S - t); start at chunk head, then multiply by 1/gamma
    float w = exp2f(LOG2_GAMMA * (float)(S - t0));

    float ax = 0.f, ay = 0.f, az = 0.f, aw = 0.f;   // local prefix of lp (t<T only)
    float Ax = 0.f, Ay = 0.f, Az = 0.f, Aw = 0.f;
    float Wx = 0.f, Wy = 0.f, Wz = 0.f, Ww = 0.f;

    #pragma unroll 4
    for (int i = 0; i < CT; ++i) {
        int t = t0 + i;
        float4 l = lp_p[(size_t)i * (B * V / 4)];
        float4 x = lg_p[(size_t)i * (V / 4)];
        if (t < T_LIM) {                 // wave-uniform branch
            ax += l.x; ay += l.y; az += l.z; aw += l.w;
        }
        float sx = w * log_sigmoid(x.x);
        float sy = w * log_sigmoid(x.y);
        float sz = w * log_sigmoid(x.z);
        float sw = w * log_sigmoid(x.w);
        Ax = fmaf(sx, ax, Ax);
        Ay = fmaf(sy, ay, Ay);
        Az = fmaf(sz, az, Az);
        Aw = fmaf(sw, aw, Aw);
        Wx += sx; Wy += sy; Wz += sz; Ww += sw;
        w *= INV_GAMMA;
    }

    pA[tid] = make_float4(Ax, Ay, Az, Aw);
    if (pW) {
        pW[tid] = make_float4(Wx, Wy, Wz, Ww);
        pL[tid] = make_float4(ax, ay, az, aw);
    }
}

// One thread per (b,v): serial prefix over NC chunk partials.
__global__ __launch_bounds__(256) void combine_kernel(
    const float* __restrict__ pA,
    const float* __restrict__ pW,
    const float* __restrict__ pL,
    float* __restrict__ out, int NC)
{
    int tid = blockIdx.x * blockDim.x + threadIdx.x;   // = b*V + v
    if (tid >= B * V) return;
    float prefix = 0.f, E = 0.f;
    for (int c = 0; c < NC; ++c) {
        int idx = c * (B * V) + tid;
        E = fmaf(prefix, pW[idx], E + pA[idx]);
        prefix += pL[idx];
    }
    out[tid] = E;
}

extern "C" void kernel_launch(void* const* d_in, const int* in_sizes, int n_in,
                              void* d_out, int out_size, void* d_ws, size_t ws_size,
                              hipStream_t stream)
{
    const float4* lp = (const float4*)d_in[0];   // log_probs [S,B,V] f32
    const float4* lg = (const float4*)d_in[1];   // logits    [B,S,V] f32
    float* out = (float*)d_out;                   // [B,V] f32

    // pick NC (power of two) so the 3 partial arrays fit in ws
    int NC = 128;
    while (NC > 1 && (size_t)NC * (B * V) * 3 * sizeof(float) > ws_size) NC >>= 1;

    if ((size_t)(B * V) * 3 * sizeof(float) > ws_size) {
        // no usable workspace: single chunk over all of S, A == E, write directly
        partials_kernel<<<(B * V / 4 + 255) / 256, 256, 0, stream>>>(
            lp, lg, (float4*)d_out, nullptr, nullptr, 1, S);
        return;
    }

    size_t per = (size_t)NC * (B * V);            // floats per partial array
    float* pA = (float*)d_ws;
    float* pW = pA + per;
    float* pL = pW + per;
    int CT = S / NC;

    int threads1 = NC * (B * V / 4);
    partials_kernel<<<(threads1 + 255) / 256, 256, 0, stream>>>(
        lp, lg, (float4*)pA, (float4*)pW, (float4*)pL, NC, CT);
    combine_kernel<<<(B * V + 255) / 256, 256, 0, stream>>>(pA, pW, pL, out, NC);
}

// Round 3
// 109.569 us; speedup vs baseline: 1.3557x; 1.3557x over previous
//
#include <hip/hip_runtime.h>

#define B 16
#define S 4096
#define V 128
#define TRUNC 11
#define T_LIM (S - TRUNC)   // 4085

#define NC 256              // chunks over t
#define CT (S / NC)         // 16

// log2(0.99), 1/0.99
#define LOG2_GAMMA (-0.014499569695115089f)
#define INV_GAMMA 1.0101010101010102f

__device__ __forceinline__ float log_sigmoid(float x) {
    float e = __expf(-fabsf(x));
    return fminf(x, 0.0f) - __logf(1.0f + e);
}

// Thread (c, b, v4): per v in the float4 group computes
//   A = sum_{t in chunk} w[t]*ls[t]*local_acc[t]
//   W = sum_{t in chunk} w[t]*ls[t]
//   L = sum_{t in chunk, t<T} lp[t]
// Stores TRANSPOSED: p*[bv*nc + c] so the combine wave reads contiguously.
// writeWL==0: direct-output fallback (nc==1, pA == out).
__global__ __launch_bounds__(256) void partials_kernel(
    const float4* __restrict__ lp,   // [S][B][V/4]
    const float4* __restrict__ lg,   // [B][S][V/4]
    float* __restrict__ pA,          // [B*V][nc]
    float* __restrict__ pW,
    float* __restrict__ pL,
    int nc, int ct, int writeWL)
{
    int tid = blockIdx.x * blockDim.x + threadIdx.x;
    if (tid >= nc * (B * V / 4)) return;
    int v4 = tid & (V / 4 - 1);          // 0..31
    int b  = (tid >> 5) & (B - 1);       // 0..15
    int c  = tid >> 9;                   // chunk
    int t0 = c * ct;

    const float4* lp_p = lp + (size_t)t0 * (B * V / 4) + b * (V / 4) + v4;
    const float4* lg_p = lg + (size_t)b * (S * V / 4) + (size_t)t0 * (V / 4) + v4;

    float w = exp2f(LOG2_GAMMA * (float)(S - t0));

    float ax = 0.f, ay = 0.f, az = 0.f, aw = 0.f;
    float Ax = 0.f, Ay = 0.f, Az = 0.f, Aw = 0.f;
    float Wx = 0.f, Wy = 0.f, Wz = 0.f, Ww = 0.f;

    #pragma unroll 4
    for (int i = 0; i < ct; ++i) {
        int t = t0 + i;
        float4 l = lp_p[(size_t)i * (B * V / 4)];
        float4 x = lg_p[(size_t)i * (V / 4)];
        if (t < T_LIM) {                 // wave-uniform
            ax += l.x; ay += l.y; az += l.z; aw += l.w;
        }
        float sx = w * log_sigmoid(x.x);
        float sy = w * log_sigmoid(x.y);
        float sz = w * log_sigmoid(x.z);
        float sw = w * log_sigmoid(x.w);
        Ax = fmaf(sx, ax, Ax);
        Ay = fmaf(sy, ay, Ay);
        Az = fmaf(sz, az, Az);
        Aw = fmaf(sw, aw, Aw);
        Wx += sx; Wy += sy; Wz += sz; Ww += sw;
        w *= INV_GAMMA;
    }

    int bv0 = b * V + v4 * 4;
    float As[4] = {Ax, Ay, Az, Aw};
    float Ws[4] = {Wx, Wy, Wz, Ww};
    float Ls[4] = {ax, ay, az, aw};
    #pragma unroll
    for (int j = 0; j < 4; ++j) {
        size_t idx = (size_t)(bv0 + j) * nc + c;
        pA[idx] = As[j];
        if (writeWL) { pW[idx] = Ws[j]; pL[idx] = Ls[j]; }
    }
}

// One wave per (b,v). Lane l owns chunks 4l..4l+3 (one float4 per array).
// Exclusive scan of L across chunks -> prefix; E = sum(A + prefix*W).
__global__ __launch_bounds__(256) void combine_kernel(
    const float4* __restrict__ pA,   // [B*V][NC/4]
    const float4* __restrict__ pW,
    const float4* __restrict__ pL,
    float* __restrict__ out)
{
    int gtid = blockIdx.x * blockDim.x + threadIdx.x;
    int bv   = gtid >> 6;
    int lane = threadIdx.x & 63;
    if (bv >= B * V) return;

    const int nc4 = NC / 4;              // 64 float4 per row
    float4 A = pA[(size_t)bv * nc4 + lane];
    float4 W = pW[(size_t)bv * nc4 + lane];
    float4 L = pL[(size_t)bv * nc4 + lane];

    // intra-lane exclusive prefixes over the 4 chunks
    float p1 = L.x;
    float p2 = p1 + L.y;
    float p3 = p2 + L.z;
    float s  = p3 + L.w;                 // lane total

    // inclusive wave scan of s, then make exclusive
    float scan = s;
    #pragma unroll
    for (int off = 1; off < 64; off <<= 1) {
        float n = __shfl_up(scan, off, 64);
        if (lane >= off) scan += n;
    }
    float base = scan - s;               // exclusive prefix across lanes

    float E = A.x + A.y + A.z + A.w;
    E = fmaf(base,      W.x, E);
    E = fmaf(base + p1, W.y, E);
    E = fmaf(base + p2, W.z, E);
    E = fmaf(base + p3, W.w, E);

    // wave reduction
    #pragma unroll
    for (int off = 32; off > 0; off >>= 1)
        E += __shfl_down(E, off, 64);

    if (lane == 0) out[bv] = E;
}

extern "C" void kernel_launch(void* const* d_in, const int* in_sizes, int n_in,
                              void* d_out, int out_size, void* d_ws, size_t ws_size,
                              hipStream_t stream)
{
    const float4* lp = (const float4*)d_in[0];   // log_probs [S,B,V] f32
    const float4* lg = (const float4*)d_in[1];   // logits    [B,S,V] f32
    float* out = (float*)d_out;                   // [B,V] f32

    size_t per = (size_t)NC * (B * V);            // floats per partial array

    if (per * 3 * sizeof(float) > ws_size) {
        // fallback: single chunk over all of S, A == E, write directly
        partials_kernel<<<(B * V / 4 + 255) / 256, 256, 0, stream>>>(
            lp, lg, out, nullptr, nullptr, 1, S, 0);
        return;
    }

    float* pA = (float*)d_ws;
    float* pW = pA + per;
    float* pL = pW + per;

    int threads1 = NC * (B * V / 4);              // 131072
    partials_kernel<<<(threads1 + 255) / 256, 256, 0, stream>>>(
        lp, lg, pA, pW, pL, NC, CT, 1);

    // one 64-lane wave per (b,v) => B*V*64 threads total
    int threads2 = B * V * 64;                    // 131072
    combine_kernel<<<(threads2 + 255) / 256, 256, 0, stream>>>(
        (const float4*)pA, (const float4*)pW, (const float4*)pL, out);
}